// Round 2
// baseline (432.051 us; speedup 1.0000x reference)
//
#include <hip/hip_runtime.h>
#include <hip/hip_bf16.h>

// Fused elementwise: out = (x + 2) + 3*x - (x - 1) * (x / 2)
// fp32 in, fp32 out, 8192*8192 = 67,108,864 elements.
// Memory-bound: 512 MB total traffic -> ~81 us at 6.3 TB/s achievable HBM BW.

__device__ __forceinline__ float fuse_op(float x) {
    // Same order as reference for bit-closeness; VALU cost irrelevant (BW-bound).
    return (x + 2.0f) + (x * 3.0f) - (x - 1.0f) * (x * 0.5f);
}

__global__ __launch_bounds__(256) void fused_elem_kernel(const float* __restrict__ x,
                                                         float* __restrict__ out,
                                                         int n4) {
    // n4 = number of float4 elements = 16,777,216 (fits int32)
    int idx = blockIdx.x * blockDim.x + threadIdx.x;
    int stride = gridDim.x * blockDim.x;
    const float4* __restrict__ xin = (const float4*)x;
    float4* __restrict__ o4 = (float4*)out;
    for (int i = idx; i < n4; i += stride) {
        float4 v = xin[i];
        float4 r;
        r.x = fuse_op(v.x);
        r.y = fuse_op(v.y);
        r.z = fuse_op(v.z);
        r.w = fuse_op(v.w);
        o4[i] = r;
    }
}

extern "C" void kernel_launch(void* const* d_in, const int* in_sizes, int n_in,
                              void* d_out, int out_size, void* d_ws, size_t ws_size,
                              hipStream_t stream) {
    const float* x = (const float*)d_in[0];
    float* out = (float*)d_out;
    long long n = (long long)in_sizes[0];   // 67,108,864
    int n4 = (int)(n / 4);                  // 16,777,216

    const int block = 256;
    // Cap grid at ~2048 blocks (256 CUs x 8 blocks/CU), grid-stride the rest.
    long long want = ((long long)n4 + block - 1) / block;
    int grid = (int)(want < 2048 ? want : 2048);

    fused_elem_kernel<<<grid, block, 0, stream>>>(x, out, n4);
}